// Round 7
// baseline (181.260 us; speedup 1.0000x reference)
//
#include <hip/hip_runtime.h>
#include <hip/hip_bf16.h>
#include <cstdint>
#include <cstddef>

typedef __bf16 bf16x8 __attribute__((ext_vector_type(8)));
typedef _Float16 f16x8 __attribute__((ext_vector_type(8)));
typedef short short8 __attribute__((ext_vector_type(8)));
typedef short short4v __attribute__((ext_vector_type(4)));
typedef float f32x4 __attribute__((ext_vector_type(4)));

__device__ __forceinline__ unsigned short f2bf(float f) {
    union { float f; uint32_t u; } v; v.f = f;
    uint32_t u = v.u;
    return (unsigned short)((u + 0x7FFFu + ((u >> 16) & 1u)) >> 16);
}
__device__ __forceinline__ float bf2f(unsigned short h) {
    union { uint32_t u; float f; } v; v.u = ((uint32_t)h) << 16;
    return v.f;
}
__device__ __forceinline__ unsigned short f2h(float f) {
    union { _Float16 h; unsigned short u; } v; v.h = (_Float16)f;
    return v.u;
}

// ---------------------------------------------------------------------------
// Kernel 0: preconvert weights.
// bid 0..11 : (proj,kc): W[256][128] fp32 -> wt_hi/wt_lo [proj][kc][128n][64k] bf16
// bid 12..15: Wo[128][256] fp32 -> wot[256c][128a] bf16
// bid 16    : gamma[c] = tanh(relu(1 + wg[c]))
// ---------------------------------------------------------------------------
__global__ __launch_bounds__(256) void prep_kernel(
    const float* __restrict__ Wq, const float* __restrict__ Wk,
    const float* __restrict__ Wv, const float* __restrict__ Wo,
    const float* __restrict__ wg,
    unsigned short* __restrict__ wt_hi,
    unsigned short* __restrict__ wt_lo,
    unsigned short* __restrict__ wot,
    float* __restrict__ gamma)
{
    const int bid = blockIdx.x, t = threadIdx.x;
    __shared__ __align__(16) unsigned short Th[128][72], Tl[128][72];
    if (bid < 12) {
        const int proj = bid >> 2, kc = bid & 3;
        const float* W = (proj == 0) ? Wq : ((proj == 1) ? Wk : Wv);
        for (int r = 0; r < 32; ++r) {
            int idx = r * 256 + t;
            int kk = idx >> 7, n = idx & 127;
            float w = W[(size_t)(kc * 64 + kk) * 128 + n];
            unsigned short h = f2bf(w);
            Th[n][kk] = h;
            Tl[n][kk] = f2bf(w - bf2f(h));
        }
        __syncthreads();
        int n = t >> 1, k0 = (t & 1) * 32;
        size_t off = (size_t)proj * 32768 + (size_t)kc * 8192 + (size_t)n * 64 + k0;
        #pragma unroll
        for (int j = 0; j < 4; ++j) {
            *(short8*)(wt_hi + off + j * 8) = *(const short8*)(&Th[n][k0 + j * 8]);
            *(short8*)(wt_lo + off + j * 8) = *(const short8*)(&Tl[n][k0 + j * 8]);
        }
    } else if (bid < 16) {
        const int c0 = (bid - 12) * 64;
        unsigned short* T = &Th[0][0];         // 64c x 128a, stride 136
        for (int r = 0; r < 32; ++r) {
            int idx = r * 256 + t;
            int a = idx >> 6, cc = idx & 63;
            T[cc * 136 + a] = f2bf(Wo[(size_t)a * 256 + c0 + cc]);
        }
        __syncthreads();
        int cc = t >> 2, a0 = (t & 3) * 32;
        #pragma unroll
        for (int j = 0; j < 4; ++j)
            *(short8*)(wot + (size_t)(c0 + cc) * 128 + a0 + j * 8) =
                *(const short8*)(&T[cc * 136 + a0 + j * 8]);
    } else {
        float g = 1.0f + wg[t];
        if (g < 0.f) g = 0.f;
        gamma[t] = tanhf(g);
    }
}

// ---------------------------------------------------------------------------
// Kernel 1: q/k/v = leaky_relu(x @ W). x fp32 (inline hi/lo conversion);
// W preconverted bf16 hi/lo. q,k 3-term fp32-accurate -> fp16;
// v -> bf16 transposed vt[b][d][4096]. grid (256, 3), block 256.
// ---------------------------------------------------------------------------
__global__ __launch_bounds__(256) void qkv_kernel(
    const float* __restrict__ x,
    const unsigned short* __restrict__ wt_hi,
    const unsigned short* __restrict__ wt_lo,
    unsigned short* __restrict__ qkv_ws)
{
    const int rowtile = blockIdx.x;
    const int proj    = blockIdx.y;
    unsigned short* outqk = qkv_ws + (size_t)proj * 2097152u;
    unsigned short* vt    = qkv_ws + (size_t)2 * 2097152u;
    const bool need_lo = (proj < 2);

    const int tid  = threadIdx.x;
    const int lane = tid & 63, wave = tid >> 6;
    const int lo   = lane & 15, quad = lane >> 4;

    __shared__ __align__(16) unsigned short Xh[64][72], Xl[64][72];
    __shared__ __align__(16) unsigned short Wh[128][72], Wl[128][72];

    f32x4 acc[8];
    #pragma unroll
    for (int i = 0; i < 8; ++i) acc[i] = (f32x4){0.f, 0.f, 0.f, 0.f};

    const int wn = tid >> 1, wk0 = (tid & 1) * 32;

    for (int kc = 0; kc < 4; ++kc) {
        __syncthreads();
        #pragma unroll
        for (int i = 0; i < 4; ++i) {
            int flat4 = (i * 256 + tid) * 4;
            int row = flat4 >> 6, col = flat4 & 63;
            float4 tv4 = *(const float4*)(x + (size_t)(rowtile * 64 + row) * 256 + kc * 64 + col);
            float tv[4] = {tv4.x, tv4.y, tv4.z, tv4.w};
            short4v h, l;
            #pragma unroll
            for (int j = 0; j < 4; ++j) {
                unsigned short hj = f2bf(tv[j]);
                h[j] = (short)hj;
                l[j] = (short)f2bf(tv[j] - bf2f(hj));
            }
            *(short4v*)(&Xh[row][col]) = h;
            if (need_lo) *(short4v*)(&Xl[row][col]) = l;
        }
        {
            const size_t off = (size_t)proj * 32768 + (size_t)kc * 8192 + (size_t)wn * 64 + wk0;
            #pragma unroll
            for (int j = 0; j < 4; ++j)
                *(short8*)(&Wh[wn][wk0 + j * 8]) = *(const short8*)(wt_hi + off + j * 8);
            if (need_lo) {
                #pragma unroll
                for (int j = 0; j < 4; ++j)
                    *(short8*)(&Wl[wn][wk0 + j * 8]) = *(const short8*)(wt_lo + off + j * 8);
            }
        }
        __syncthreads();
        #pragma unroll
        for (int ks = 0; ks < 2; ++ks) {
            bf16x8 ah = *(const bf16x8*)(&Xh[wave * 16 + lo][ks * 32 + quad * 8]);
            #pragma unroll
            for (int nb = 0; nb < 8; ++nb) {
                bf16x8 bh = *(const bf16x8*)(&Wh[nb * 16 + lo][ks * 32 + quad * 8]);
                acc[nb] = __builtin_amdgcn_mfma_f32_16x16x32_bf16(ah, bh, acc[nb], 0, 0, 0);
                if (need_lo) {
                    bf16x8 al = *(const bf16x8*)(&Xl[wave * 16 + lo][ks * 32 + quad * 8]);
                    bf16x8 bl = *(const bf16x8*)(&Wl[nb * 16 + lo][ks * 32 + quad * 8]);
                    acc[nb] = __builtin_amdgcn_mfma_f32_16x16x32_bf16(al, bh, acc[nb], 0, 0, 0);
                    acc[nb] = __builtin_amdgcn_mfma_f32_16x16x32_bf16(ah, bl, acc[nb], 0, 0, 0);
                }
            }
        }
    }
    if (proj < 2) {
        #pragma unroll
        for (int nb = 0; nb < 8; ++nb) {
            #pragma unroll
            for (int r = 0; r < 4; ++r) {
                float v = acc[nb][r];
                v = (v >= 0.f) ? v : 0.2f * v;
                int m = rowtile * 64 + wave * 16 + quad * 4 + r;
                outqk[(size_t)m * 128 + nb * 16 + lo] = f2h(v);
            }
        }
    } else {
        const int b  = rowtile >> 6;
        const int sb = (rowtile & 63) * 64;
        #pragma unroll
        for (int nb = 0; nb < 8; ++nb) {
            #pragma unroll
            for (int r = 0; r < 4; ++r) {
                float v = acc[nb][r];
                v = (v >= 0.f) ? v : 0.2f * v;
                int seq = sb + wave * 16 + quad * 4 + r;
                int d   = nb * 16 + lo;
                vt[(size_t)b * 524288 + (size_t)d * 4096 + seq] = f2bf(v);
            }
        }
    }
}

// ---------------------------------------------------------------------------
// Kernel 2: flash attention, fixed-shift softmax, fp16 QK^T, K-split partials.
// Double-buffered LDS (ONE barrier per tile), V in 4 chunk-planes (conflict-free).
// 32 q-rows/wave, KT=32. grid (4, 32, nsplit), block 256.
// ---------------------------------------------------------------------------
__global__ __launch_bounds__(256) void attn_kernel(
    const unsigned short* __restrict__ qkv_ws,
    unsigned short* __restrict__ part,   // [nsplit][16384][128] bf16
    float* __restrict__ lpart,           // [nsplit][16384] fp32
    int chunk)
{
    const int b  = blockIdx.x;
    const int qt = blockIdx.y;
    const int z  = blockIdx.z;
    const int tid  = threadIdx.x;
    const int lane = tid & 63, wave = tid >> 6;
    const int lo   = lane & 15, quad = lane >> 4;

    const unsigned short* q  = qkv_ws;
    const unsigned short* k  = qkv_ws + 2097152u;
    const unsigned short* vt = qkv_ws + (size_t)2 * 2097152u + (size_t)b * 524288u;

    __shared__ __align__(16) unsigned short Ks[2][32][136];     // K fp16 [seq][d]
    __shared__ __align__(16) unsigned short Vt4[2][4][128][8];  // V^T bf16 chunk-planes
    __shared__ __align__(16) unsigned short Ps[4][32][40];      // per-wave P bf16

    const int qbase = qt * 128 + wave * 32;
    f16x8 qf[2][4];
    #pragma unroll
    for (int g = 0; g < 2; ++g)
        #pragma unroll
        for (int ks = 0; ks < 4; ++ks)
            qf[g][ks] = *(const f16x8*)(q + ((size_t)(b * 4096 + qbase + g * 16 + lo)) * 128
                                          + ks * 32 + quad * 8);

    f32x4 oacc[2][8];
    #pragma unroll
    for (int g = 0; g < 2; ++g)
        #pragma unroll
        for (int i = 0; i < 8; ++i) oacc[g][i] = (f32x4){0.f, 0.f, 0.f, 0.f};
    float lsum[2][4];
    #pragma unroll
    for (int g = 0; g < 2; ++g)
        #pragma unroll
        for (int r = 0; r < 4; ++r) lsum[g][r] = 1e-30f;

    const float LOG2E  = 1.44269504088896f;
    const float NSHIFT = -40.0f * 1.44269504088896f;

    // staging maps: K two b128/thread; V two b128/thread into chunk-planes
    const int krow0 = tid >> 4, kcol0 = (tid & 15) * 8;
    const int krow1 = 16 + (tid >> 4);
    const int vd = tid >> 2, vc = tid & 3;   // d-row (0..63 / 64..127), s-chunk

    const int niter = chunk >> 5;
    const int sbase = z * chunk;

    short8 ka, kb, va, vb;
    ka = *(const short8*)(k + ((size_t)(b * 4096 + sbase + krow0)) * 128 + kcol0);
    kb = *(const short8*)(k + ((size_t)(b * 4096 + sbase + krow1)) * 128 + kcol0);
    va = *(const short8*)(vt + (size_t)vd * 4096 + sbase + vc * 8);
    vb = *(const short8*)(vt + (size_t)(vd + 64) * 4096 + sbase + vc * 8);
    *(short8*)(&Ks[0][krow0][kcol0]) = ka;
    *(short8*)(&Ks[0][krow1][kcol0]) = kb;
    *(short8*)(&Vt4[0][vc][vd][0]) = va;
    *(short8*)(&Vt4[0][vc][vd + 64][0]) = vb;
    __syncthreads();

    for (int kt = 0; kt < niter; ++kt) {
        const int cur = kt & 1, nxt = cur ^ 1;
        const bool more = (kt + 1 < niter);
        if (more) {   // issue prefetch early; vmcnt wait lands at the ds_writes below
            const int s1 = sbase + (kt + 1) * 32;
            ka = *(const short8*)(k + ((size_t)(b * 4096 + s1 + krow0)) * 128 + kcol0);
            kb = *(const short8*)(k + ((size_t)(b * 4096 + s1 + krow1)) * 128 + kcol0);
            va = *(const short8*)(vt + (size_t)vd * 4096 + s1 + vc * 8);
            vb = *(const short8*)(vt + (size_t)(vd + 64) * 4096 + s1 + vc * 8);
        }

        // S = q k^T (fp16): per wave 32x32 = 16 MFMAs, B-frags shared across g
        f32x4 s[2][2];
        s[0][0] = (f32x4){0.f,0.f,0.f,0.f}; s[0][1] = (f32x4){0.f,0.f,0.f,0.f};
        s[1][0] = (f32x4){0.f,0.f,0.f,0.f}; s[1][1] = (f32x4){0.f,0.f,0.f,0.f};
        #pragma unroll
        for (int ks = 0; ks < 4; ++ks) {
            #pragma unroll
            for (int nb = 0; nb < 2; ++nb) {
                f16x8 bf = *(const f16x8*)(&Ks[cur][nb * 16 + lo][ks * 32 + quad * 8]);
                s[0][nb] = __builtin_amdgcn_mfma_f32_16x16x32_f16(qf[0][ks], bf, s[0][nb], 0, 0, 0);
                s[1][nb] = __builtin_amdgcn_mfma_f32_16x16x32_f16(qf[1][ks], bf, s[1][nb], 0, 0, 0);
            }
        }
        // P = exp(s - 40), truncated to bf16 (lsum uses truncated value -> bias cancels)
        #pragma unroll
        for (int g = 0; g < 2; ++g) {
            #pragma unroll
            for (int nb = 0; nb < 2; ++nb) {
                #pragma unroll
                for (int r = 0; r < 4; ++r) {
                    float t = fminf(fmaf(s[g][nb][r], LOG2E, NSHIFT), 125.0f);
                    union { float f; uint32_t u; } pv; pv.f = exp2f(t);
                    unsigned short pt = (unsigned short)(pv.u >> 16);
                    lsum[g][r] += bf2f(pt);
                    Ps[wave][g * 16 + quad * 4 + r][nb * 16 + lo] = pt;
                }
            }
        }
        // PV: O += P V (within-wave ds ordering; Vt4 plane = s-chunk = quad)
        bf16x8 pf0 = *(const bf16x8*)(&Ps[wave][lo][quad * 8]);
        bf16x8 pf1 = *(const bf16x8*)(&Ps[wave][16 + lo][quad * 8]);
        #pragma unroll
        for (int nb = 0; nb < 8; ++nb) {
            bf16x8 vf = *(const bf16x8*)(&Vt4[cur][quad][nb * 16 + lo][0]);
            oacc[0][nb] = __builtin_amdgcn_mfma_f32_16x16x32_bf16(pf0, vf, oacc[0][nb], 0, 0, 0);
            oacc[1][nb] = __builtin_amdgcn_mfma_f32_16x16x32_bf16(pf1, vf, oacc[1][nb], 0, 0, 0);
        }
        // stage next tile into the other buffer, then ONE barrier
        if (more) {
            *(short8*)(&Ks[nxt][krow0][kcol0]) = ka;
            *(short8*)(&Ks[nxt][krow1][kcol0]) = kb;
            *(short8*)(&Vt4[nxt][vc][vd][0]) = va;
            *(short8*)(&Vt4[nxt][vc][vd + 64][0]) = vb;
        }
        __syncthreads();
    }

    #pragma unroll
    for (int g = 0; g < 2; ++g) {
        #pragma unroll
        for (int r = 0; r < 4; ++r) {
            float xr = lsum[g][r];
            #pragma unroll
            for (int m = 1; m < 16; m <<= 1) xr += __shfl_xor(xr, m, 64);
            lsum[g][r] = xr;
        }
        #pragma unroll
        for (int nb = 0; nb < 8; ++nb) {
            #pragma unroll
            for (int r = 0; r < 4; ++r) {
                int m = b * 4096 + qbase + g * 16 + quad * 4 + r;
                part[((size_t)z * 16384 + m) * 128 + nb * 16 + lo] = f2bf(oacc[g][nb][r]);
            }
        }
        if (lo == 0) {
            #pragma unroll
            for (int r = 0; r < 4; ++r) {
                int m = b * 4096 + qbase + g * 16 + quad * 4 + r;
                lpart[(size_t)z * 16384 + m] = lsum[g][r];
            }
        }
    }
}

// ---------------------------------------------------------------------------
// Kernel 3: combine partials once; y = (o @ Wo) * gamma, both col-halves per block.
// grid 256 row-tiles, block 256.
// ---------------------------------------------------------------------------
__global__ __launch_bounds__(256) void outproj_kernel(
    const unsigned short* __restrict__ part,
    const float* __restrict__ lpart,
    const unsigned short* __restrict__ wot,
    const float* __restrict__ gamma,
    float* __restrict__ out,
    int nsplit)
{
    const int rowtile = blockIdx.x;
    const int tid  = threadIdx.x;
    const int lane = tid & 63, wave = tid >> 6;
    const int lo   = lane & 15, quad = lane >> 4;

    __shared__ __align__(16) unsigned short Os[64][136];
    __shared__ __align__(16) unsigned short WoT[128][136];

    #pragma unroll
    for (int i = 0; i < 4; ++i) {
        int flat = (i * 256 + tid) * 8;
        int row = flat >> 7, col = flat & 127;
        int m = rowtile * 64 + row;
        float acc8[8] = {0.f,0.f,0.f,0.f,0.f,0.f,0.f,0.f};
        float l = 0.f;
        for (int zz = 0; zz < nsplit; ++zz) {
            short8 t = *(const short8*)(part + ((size_t)zz * 16384 + m) * 128 + col);
            #pragma unroll
            for (int j = 0; j < 8; ++j) acc8[j] += bf2f((unsigned short)t[j]);
            l += lpart[(size_t)zz * 16384 + m];
        }
        float inv = 1.0f / l;
        short8 o8;
        #pragma unroll
        for (int j = 0; j < 8; ++j) o8[j] = (short)f2bf(acc8[j] * inv);
        *(short8*)(&Os[row][col]) = o8;
    }

    const int wc = tid >> 1, wa0 = (tid & 1) * 64;
    for (int ch = 0; ch < 2; ++ch) {
        if (ch) __syncthreads();
        #pragma unroll
        for (int j = 0; j < 8; ++j)
            *(short8*)(&WoT[wc][wa0 + j * 8]) =
                *(const short8*)(wot + (size_t)(ch * 128 + wc) * 128 + wa0 + j * 8);
        __syncthreads();

        f32x4 acc[8];
        #pragma unroll
        for (int i = 0; i < 8; ++i) acc[i] = (f32x4){0.f, 0.f, 0.f, 0.f};
        #pragma unroll
        for (int ks = 0; ks < 4; ++ks) {
            bf16x8 a = *(const bf16x8*)(&Os[wave * 16 + lo][ks * 32 + quad * 8]);
            #pragma unroll
            for (int nb = 0; nb < 8; ++nb) {
                bf16x8 bf = *(const bf16x8*)(&WoT[nb * 16 + lo][ks * 32 + quad * 8]);
                acc[nb] = __builtin_amdgcn_mfma_f32_16x16x32_bf16(a, bf, acc[nb], 0, 0, 0);
            }
        }
        #pragma unroll
        for (int nb = 0; nb < 8; ++nb) {
            int c = ch * 128 + nb * 16 + lo;
            float g = gamma[c];
            #pragma unroll
            for (int r = 0; r < 4; ++r) {
                int m = rowtile * 64 + wave * 16 + quad * 4 + r;
                out[(size_t)m * 256 + c] = acc[nb][r] * g;
            }
        }
    }
}

// ---------------------------------------------------------------------------
extern "C" void kernel_launch(void* const* d_in, const int* in_sizes, int n_in,
                              void* d_out, int out_size, void* d_ws, size_t ws_size,
                              hipStream_t stream) {
    const float* x  = (const float*)d_in[0];
    const float* Wq = (const float*)d_in[1];
    const float* Wk = (const float*)d_in[2];
    const float* Wv = (const float*)d_in[3];
    const float* Wo = (const float*)d_in[4];
    const float* wg = (const float*)d_in[5];
    float* out = (float*)d_out;

    unsigned short* ws = (unsigned short*)d_ws;
    const int nsplit = (ws_size >= (size_t)47000000) ? 8 : 4;
    const int chunk  = 4096 / nsplit;

    // layout (2B units): qkv_ws 3*2Mi | part nsplit*2Mi | lpart | wot | gamma
    // wt_hi/wt_lo overlay at part start (consumed by qkv before attn writes part)
    unsigned short* qkv_ws = ws;
    unsigned short* part   = ws + (size_t)3 * 2097152u;
    unsigned short* wt_hi  = part;
    unsigned short* wt_lo  = part + 98304u;
    float* lpart = (float*)(part + (size_t)nsplit * 2097152u);
    unsigned short* wot = (unsigned short*)(lpart + (size_t)nsplit * 16384u);
    float* gamma = (float*)(wot + 32768u);

    prep_kernel<<<dim3(17), 256, 0, stream>>>(Wq, Wk, Wv, Wo, wg, wt_hi, wt_lo, wot, gamma);
    qkv_kernel<<<dim3(256, 3), 256, 0, stream>>>(x, wt_hi, wt_lo, qkv_ws);
    attn_kernel<<<dim3(4, 32, nsplit), 256, 0, stream>>>(qkv_ws, part, lpart, chunk);
    outproj_kernel<<<dim3(256), 256, 0, stream>>>(part, lpart, wot, gamma, out, nsplit);
}

// Round 8
// 178.052 us; speedup vs baseline: 1.0180x; 1.0180x over previous
//
#include <hip/hip_runtime.h>
#include <hip/hip_bf16.h>
#include <cstdint>
#include <cstddef>

typedef __bf16 bf16x8 __attribute__((ext_vector_type(8)));
typedef _Float16 f16x8 __attribute__((ext_vector_type(8)));
typedef short short8 __attribute__((ext_vector_type(8)));
typedef short short4v __attribute__((ext_vector_type(4)));
typedef float f32x4 __attribute__((ext_vector_type(4)));

#if __has_builtin(__builtin_amdgcn_mfma_f32_16x16x16bf16_1k)
  #define HAVE_K16 1
  #define MFMA16BF(a,b,c) __builtin_amdgcn_mfma_f32_16x16x16bf16_1k((a),(b),(c),0,0,0)
#elif __has_builtin(__builtin_amdgcn_mfma_f32_16x16x16_bf16)
  #define HAVE_K16 1
  #define MFMA16BF(a,b,c) __builtin_amdgcn_mfma_f32_16x16x16_bf16((a),(b),(c),0,0,0)
#else
  #define HAVE_K16 0
#endif

__device__ __forceinline__ unsigned short f2bf(float f) {
    union { float f; uint32_t u; } v; v.f = f;
    uint32_t u = v.u;
    return (unsigned short)((u + 0x7FFFu + ((u >> 16) & 1u)) >> 16);
}
__device__ __forceinline__ float bf2f(unsigned short h) {
    union { uint32_t u; float f; } v; v.u = ((uint32_t)h) << 16;
    return v.f;
}
__device__ __forceinline__ unsigned short f2h(float f) {
    union { _Float16 h; unsigned short u; } v; v.h = (_Float16)f;
    return v.u;
}

// ---------------------------------------------------------------------------
// Kernel 0: preconvert weights (unchanged from round 7).
// ---------------------------------------------------------------------------
__global__ __launch_bounds__(256) void prep_kernel(
    const float* __restrict__ Wq, const float* __restrict__ Wk,
    const float* __restrict__ Wv, const float* __restrict__ Wo,
    const float* __restrict__ wg,
    unsigned short* __restrict__ wt_hi,
    unsigned short* __restrict__ wt_lo,
    unsigned short* __restrict__ wot,
    float* __restrict__ gamma)
{
    const int bid = blockIdx.x, t = threadIdx.x;
    __shared__ __align__(16) unsigned short Th[128][72], Tl[128][72];
    if (bid < 12) {
        const int proj = bid >> 2, kc = bid & 3;
        const float* W = (proj == 0) ? Wq : ((proj == 1) ? Wk : Wv);
        for (int r = 0; r < 32; ++r) {
            int idx = r * 256 + t;
            int kk = idx >> 7, n = idx & 127;
            float w = W[(size_t)(kc * 64 + kk) * 128 + n];
            unsigned short h = f2bf(w);
            Th[n][kk] = h;
            Tl[n][kk] = f2bf(w - bf2f(h));
        }
        __syncthreads();
        int n = t >> 1, k0 = (t & 1) * 32;
        size_t off = (size_t)proj * 32768 + (size_t)kc * 8192 + (size_t)n * 64 + k0;
        #pragma unroll
        for (int j = 0; j < 4; ++j) {
            *(short8*)(wt_hi + off + j * 8) = *(const short8*)(&Th[n][k0 + j * 8]);
            *(short8*)(wt_lo + off + j * 8) = *(const short8*)(&Tl[n][k0 + j * 8]);
        }
    } else if (bid < 16) {
        const int c0 = (bid - 12) * 64;
        unsigned short* T = &Th[0][0];
        for (int r = 0; r < 32; ++r) {
            int idx = r * 256 + t;
            int a = idx >> 6, cc = idx & 63;
            T[cc * 136 + a] = f2bf(Wo[(size_t)a * 256 + c0 + cc]);
        }
        __syncthreads();
        int cc = t >> 2, a0 = (t & 3) * 32;
        #pragma unroll
        for (int j = 0; j < 4; ++j)
            *(short8*)(wot + (size_t)(c0 + cc) * 128 + a0 + j * 8) =
                *(const short8*)(&T[cc * 136 + a0 + j * 8]);
    } else {
        float g = 1.0f + wg[t];
        if (g < 0.f) g = 0.f;
        gamma[t] = tanhf(g);
    }
}

// ---------------------------------------------------------------------------
// Kernel 1: q/k/v projections (unchanged from round 7).
// ---------------------------------------------------------------------------
__global__ __launch_bounds__(256) void qkv_kernel(
    const float* __restrict__ x,
    const unsigned short* __restrict__ wt_hi,
    const unsigned short* __restrict__ wt_lo,
    unsigned short* __restrict__ qkv_ws)
{
    const int rowtile = blockIdx.x;
    const int proj    = blockIdx.y;
    unsigned short* outqk = qkv_ws + (size_t)proj * 2097152u;
    unsigned short* vt    = qkv_ws + (size_t)2 * 2097152u;
    const bool need_lo = (proj < 2);

    const int tid  = threadIdx.x;
    const int lane = tid & 63, wave = tid >> 6;
    const int lo   = lane & 15, quad = lane >> 4;

    __shared__ __align__(16) unsigned short Xh[64][72], Xl[64][72];
    __shared__ __align__(16) unsigned short Wh[128][72], Wl[128][72];

    f32x4 acc[8];
    #pragma unroll
    for (int i = 0; i < 8; ++i) acc[i] = (f32x4){0.f, 0.f, 0.f, 0.f};

    const int wn = tid >> 1, wk0 = (tid & 1) * 32;

    for (int kc = 0; kc < 4; ++kc) {
        __syncthreads();
        #pragma unroll
        for (int i = 0; i < 4; ++i) {
            int flat4 = (i * 256 + tid) * 4;
            int row = flat4 >> 6, col = flat4 & 63;
            float4 tv4 = *(const float4*)(x + (size_t)(rowtile * 64 + row) * 256 + kc * 64 + col);
            float tv[4] = {tv4.x, tv4.y, tv4.z, tv4.w};
            short4v h, l;
            #pragma unroll
            for (int j = 0; j < 4; ++j) {
                unsigned short hj = f2bf(tv[j]);
                h[j] = (short)hj;
                l[j] = (short)f2bf(tv[j] - bf2f(hj));
            }
            *(short4v*)(&Xh[row][col]) = h;
            if (need_lo) *(short4v*)(&Xl[row][col]) = l;
        }
        {
            const size_t off = (size_t)proj * 32768 + (size_t)kc * 8192 + (size_t)wn * 64 + wk0;
            #pragma unroll
            for (int j = 0; j < 4; ++j)
                *(short8*)(&Wh[wn][wk0 + j * 8]) = *(const short8*)(wt_hi + off + j * 8);
            if (need_lo) {
                #pragma unroll
                for (int j = 0; j < 4; ++j)
                    *(short8*)(&Wl[wn][wk0 + j * 8]) = *(const short8*)(wt_lo + off + j * 8);
            }
        }
        __syncthreads();
        #pragma unroll
        for (int ks = 0; ks < 2; ++ks) {
            bf16x8 ah = *(const bf16x8*)(&Xh[wave * 16 + lo][ks * 32 + quad * 8]);
            #pragma unroll
            for (int nb = 0; nb < 8; ++nb) {
                bf16x8 bh = *(const bf16x8*)(&Wh[nb * 16 + lo][ks * 32 + quad * 8]);
                acc[nb] = __builtin_amdgcn_mfma_f32_16x16x32_bf16(ah, bh, acc[nb], 0, 0, 0);
                if (need_lo) {
                    bf16x8 al = *(const bf16x8*)(&Xl[wave * 16 + lo][ks * 32 + quad * 8]);
                    bf16x8 bl = *(const bf16x8*)(&Wl[nb * 16 + lo][ks * 32 + quad * 8]);
                    acc[nb] = __builtin_amdgcn_mfma_f32_16x16x32_bf16(al, bh, acc[nb], 0, 0, 0);
                    acc[nb] = __builtin_amdgcn_mfma_f32_16x16x32_bf16(ah, bl, acc[nb], 0, 0, 0);
                }
            }
        }
    }
    if (proj < 2) {
        #pragma unroll
        for (int nb = 0; nb < 8; ++nb) {
            #pragma unroll
            for (int r = 0; r < 4; ++r) {
                float v = acc[nb][r];
                v = (v >= 0.f) ? v : 0.2f * v;
                int m = rowtile * 64 + wave * 16 + quad * 4 + r;
                outqk[(size_t)m * 128 + nb * 16 + lo] = f2h(v);
            }
        }
    } else {
        const int b  = rowtile >> 6;
        const int sb = (rowtile & 63) * 64;
        #pragma unroll
        for (int nb = 0; nb < 8; ++nb) {
            #pragma unroll
            for (int r = 0; r < 4; ++r) {
                float v = acc[nb][r];
                v = (v >= 0.f) ? v : 0.2f * v;
                int seq = sb + wave * 16 + quad * 4 + r;
                int d   = nb * 16 + lo;
                vt[(size_t)b * 524288 + (size_t)d * 4096 + seq] = f2bf(v);
            }
        }
    }
}

#if HAVE_K16
// ---------------------------------------------------------------------------
// Kernel 2: flash attention via S^T = K·Q^T.  P stays in REGISTERS (C-layout of
// S^T == A-layout of 16x16x16 MFMA), PV = P·V with 16x16x16 bf16.  No Ps LDS
// round-trip, no pf reads, no Ps bank conflicts.  V^T staged quad-interleaved
// so one b128 read yields both K=16 B-frags.  grid (4,32,nsplit), block 256.
// ---------------------------------------------------------------------------
__global__ __launch_bounds__(256) void attn_kernel(
    const unsigned short* __restrict__ qkv_ws,
    unsigned short* __restrict__ part,   // [nsplit][16384][128] bf16
    float* __restrict__ lpart,           // [nsplit][16384] fp32
    int chunk)
{
    const int b  = blockIdx.x;
    const int qt = blockIdx.y;
    const int z  = blockIdx.z;
    const int tid  = threadIdx.x;
    const int lane = tid & 63, wave = tid >> 6;
    const int lo   = lane & 15, quad = lane >> 4;

    const unsigned short* q  = qkv_ws;
    const unsigned short* k  = qkv_ws + 2097152u;
    const unsigned short* vt = qkv_ws + (size_t)2 * 2097152u + (size_t)b * 524288u;

    __shared__ __align__(16) unsigned short Ks[32][136];   // K fp16 [s][d]
    __shared__ __align__(16) unsigned short Vt[128][40];   // V^T bf16, col = quad_s*8 + st*4 + j

    const int qbase = qt * 128 + wave * 32;
    // Q as B-operand fragments: B[k=d][n=m]: n = lane&15 = q-row, k = quad*8+j.
    f16x8 qf[2][4];
    #pragma unroll
    for (int g = 0; g < 2; ++g)
        #pragma unroll
        for (int ks = 0; ks < 4; ++ks)
            qf[g][ks] = *(const f16x8*)(q + ((size_t)(b * 4096 + qbase + g * 16 + lo)) * 128
                                          + ks * 32 + quad * 8);

    f32x4 oacc[2][8];
    #pragma unroll
    for (int g = 0; g < 2; ++g)
        #pragma unroll
        for (int i = 0; i < 8; ++i) oacc[g][i] = (f32x4){0.f, 0.f, 0.f, 0.f};
    float Lsum[2] = {1e-30f, 1e-30f};

    const float LOG2E  = 1.44269504088896f;
    const float NSHIFT = -40.0f * 1.44269504088896f;

    // staging maps
    const int krow0 = tid >> 4, kcol0 = (tid & 15) * 8;
    const int krow1 = 16 + (tid >> 4);
    const int vd = tid >> 2, vc = tid & 3;
    const int vst  = vc >> 1;
    const int colA = ((2 * vc) & 3) * 8 + vst * 4;       // s-chunk vc*8..+3
    const int colB = ((2 * vc + 1) & 3) * 8 + vst * 4;   // s-chunk vc*8+4..+7

    const int niter = chunk >> 5;
    const int sbase = z * chunk;

    short8 ka, kb, va, vb;
    ka = *(const short8*)(k + ((size_t)(b * 4096 + sbase + krow0)) * 128 + kcol0);
    kb = *(const short8*)(k + ((size_t)(b * 4096 + sbase + krow1)) * 128 + kcol0);
    va = *(const short8*)(vt + (size_t)vd * 4096 + sbase + vc * 8);
    vb = *(const short8*)(vt + (size_t)(vd + 64) * 4096 + sbase + vc * 8);

    for (int kt = 0; kt < niter; ++kt) {
        __syncthreads();
        *(short8*)(&Ks[krow0][kcol0]) = ka;
        *(short8*)(&Ks[krow1][kcol0]) = kb;
        {
            short4v a0 = {va[0], va[1], va[2], va[3]}, a1 = {va[4], va[5], va[6], va[7]};
            short4v b0 = {vb[0], vb[1], vb[2], vb[3]}, b1 = {vb[4], vb[5], vb[6], vb[7]};
            *(short4v*)(&Vt[vd][colA])      = a0;
            *(short4v*)(&Vt[vd][colB])      = a1;
            *(short4v*)(&Vt[vd + 64][colA]) = b0;
            *(short4v*)(&Vt[vd + 64][colB]) = b1;
        }
        __syncthreads();
        if (kt + 1 < niter) {
            const int s1 = sbase + (kt + 1) * 32;
            ka = *(const short8*)(k + ((size_t)(b * 4096 + s1 + krow0)) * 128 + kcol0);
            kb = *(const short8*)(k + ((size_t)(b * 4096 + s1 + krow1)) * 128 + kcol0);
            va = *(const short8*)(vt + (size_t)vd * 4096 + s1 + vc * 8);
            vb = *(const short8*)(vt + (size_t)(vd + 64) * 4096 + s1 + vc * 8);
        }

        // S^T = K·Q^T : A = K-frag (LDS), B = Q-frag (regs). 16 MFMAs K=32.
        f32x4 sT[2][2];  // [g][st]: lane holds S^T[s = st*16+quad*4+r][m = lo]
        sT[0][0] = (f32x4){0.f,0.f,0.f,0.f}; sT[0][1] = (f32x4){0.f,0.f,0.f,0.f};
        sT[1][0] = (f32x4){0.f,0.f,0.f,0.f}; sT[1][1] = (f32x4){0.f,0.f,0.f,0.f};
        #pragma unroll
        for (int ks = 0; ks < 4; ++ks) {
            #pragma unroll
            for (int st = 0; st < 2; ++st) {
                f16x8 kf = *(const f16x8*)(&Ks[st * 16 + lo][ks * 32 + quad * 8]);
                sT[0][st] = __builtin_amdgcn_mfma_f32_16x16x32_f16(kf, qf[0][ks], sT[0][st], 0, 0, 0);
                sT[1][st] = __builtin_amdgcn_mfma_f32_16x16x32_f16(kf, qf[1][ks], sT[1][st], 0, 0, 0);
            }
        }
        // P = exp(s-40), bf16-truncated IN REGISTERS (A-frag layout: k = quad*4+j).
        short4v Pp[2][2];
        #pragma unroll
        for (int g = 0; g < 2; ++g) {
            #pragma unroll
            for (int st = 0; st < 2; ++st) {
                #pragma unroll
                for (int r = 0; r < 4; ++r) {
                    float t = fminf(fmaf(sT[g][st][r], LOG2E, NSHIFT), 125.0f);
                    union { float f; uint32_t u; } pv; pv.f = exp2f(t);
                    unsigned short pt = (unsigned short)(pv.u >> 16);
                    Lsum[g] += bf2f(pt);
                    Pp[g][st][r] = (short)pt;
                }
            }
        }
        // PV: O += P·V.  B-frag = V^T from LDS: one b128 -> both st frags. 32 MFMAs K=16.
        #pragma unroll
        for (int nb = 0; nb < 8; ++nb) {
            short8 vv = *(const short8*)(&Vt[nb * 16 + lo][quad * 8]);
            short4v v0 = {vv[0], vv[1], vv[2], vv[3]};
            short4v v1 = {vv[4], vv[5], vv[6], vv[7]};
            #pragma unroll
            for (int g = 0; g < 2; ++g) {
                oacc[g][nb] = MFMA16BF(Pp[g][0], v0, oacc[g][nb]);
                oacc[g][nb] = MFMA16BF(Pp[g][1], v1, oacc[g][nb]);
            }
        }
    }

    // Lsum: lane holds partial for m = lo; reduce over the 4 quad replicas.
    #pragma unroll
    for (int g = 0; g < 2; ++g) {
        float xr = Lsum[g];
        xr += __shfl_xor(xr, 16, 64);
        xr += __shfl_xor(xr, 32, 64);
        Lsum[g] = xr;
    }
    // oacc layout identical to rounds 4-7: row m = quad*4+r, col d = nb*16+lo.
    #pragma unroll
    for (int g = 0; g < 2; ++g) {
        #pragma unroll
        for (int nb = 0; nb < 8; ++nb) {
            #pragma unroll
            for (int r = 0; r < 4; ++r) {
                int m = b * 4096 + qbase + g * 16 + quad * 4 + r;
                part[((size_t)z * 16384 + m) * 128 + nb * 16 + lo] = f2bf(oacc[g][nb][r]);
            }
        }
        if (lane < 16) {
            int m = b * 4096 + qbase + g * 16 + lane;
            lpart[(size_t)z * 16384 + m] = Lsum[g];
        }
    }
}
#else
// ---------------------------------------------------------------------------
// Fallback (no K=16 bf16 MFMA builtin): round-7 attn kernel, verbatim.
// ---------------------------------------------------------------------------
__global__ __launch_bounds__(256) void attn_kernel(
    const unsigned short* __restrict__ qkv_ws,
    unsigned short* __restrict__ part,
    float* __restrict__ lpart,
    int chunk)
{
    const int b  = blockIdx.x;
    const int qt = blockIdx.y;
    const int z  = blockIdx.z;
    const int tid  = threadIdx.x;
    const int lane = tid & 63, wave = tid >> 6;
    const int lo   = lane & 15, quad = lane >> 4;

    const unsigned short* q  = qkv_ws;
    const unsigned short* k  = qkv_ws + 2097152u;
    const unsigned short* vt = qkv_ws + (size_t)2 * 2097152u + (size_t)b * 524288u;

    __shared__ __align__(16) unsigned short Ks[32][136];
    __shared__ __align__(16) unsigned short Vt[128][40];
    __shared__ __align__(16) unsigned short Ps[4][32][40];

    const int qbase = qt * 128 + wave * 32;
    f16x8 qf[2][4];
    #pragma unroll
    for (int g = 0; g < 2; ++g)
        #pragma unroll
        for (int ks = 0; ks < 4; ++ks)
            qf[g][ks] = *(const f16x8*)(q + ((size_t)(b * 4096 + qbase + g * 16 + lo)) * 128
                                          + ks * 32 + quad * 8);
    f32x4 oacc[2][8];
    #pragma unroll
    for (int g = 0; g < 2; ++g)
        #pragma unroll
        for (int i = 0; i < 8; ++i) oacc[g][i] = (f32x4){0.f, 0.f, 0.f, 0.f};
    float lsum[2][4];
    #pragma unroll
    for (int g = 0; g < 2; ++g)
        #pragma unroll
        for (int r = 0; r < 4; ++r) lsum[g][r] = 1e-30f;

    const float LOG2E  = 1.44269504088896f;
    const float NSHIFT = -40.0f * 1.44269504088896f;

    const int krow0 = tid >> 4, kcol0 = (tid & 15) * 8;
    const int krow1 = 16 + (tid >> 4);
    const int vd0 = tid >> 2, vs0 = (tid & 3) * 8;

    const int niter = chunk >> 5;
    const int sbase = z * chunk;

    short8 ka, kb, va, vb;
    ka = *(const short8*)(k + ((size_t)(b * 4096 + sbase + krow0)) * 128 + kcol0);
    kb = *(const short8*)(k + ((size_t)(b * 4096 + sbase + krow1)) * 128 + kcol0);
    va = *(const short8*)(vt + (size_t)vd0 * 4096 + sbase + vs0);
    vb = *(const short8*)(vt + (size_t)(vd0 + 64) * 4096 + sbase + vs0);

    for (int kt = 0; kt < niter; ++kt) {
        __syncthreads();
        *(short8*)(&Ks[krow0][kcol0]) = ka;
        *(short8*)(&Ks[krow1][kcol0]) = kb;
        *(short8*)(&Vt[vd0][vs0]) = va;
        *(short8*)(&Vt[vd0 + 64][vs0]) = vb;
        __syncthreads();
        if (kt + 1 < niter) {
            const int s1 = sbase + (kt + 1) * 32;
            ka = *(const short8*)(k + ((size_t)(b * 4096 + s1 + krow0)) * 128 + kcol0);
            kb = *(const short8*)(k + ((size_t)(b * 4096 + s1 + krow1)) * 128 + kcol0);
            va = *(const short8*)(vt + (size_t)vd0 * 4096 + s1 + vs0);
            vb = *(const short8*)(vt + (size_t)(vd0 + 64) * 4096 + s1 + vs0);
        }
        f32x4 s[2][2];
        s[0][0] = (f32x4){0.f,0.f,0.f,0.f}; s[0][1] = (f32x4){0.f,0.f,0.f,0.f};
        s[1][0] = (f32x4){0.f,0.f,0.f,0.f}; s[1][1] = (f32x4){0.f,0.f,0.f,0.f};
        #pragma unroll
        for (int ks = 0; ks < 4; ++ks) {
            #pragma unroll
            for (int nb = 0; nb < 2; ++nb) {
                f16x8 bf = *(const f16x8*)(&Ks[nb * 16 + lo][ks * 32 + quad * 8]);
                s[0][nb] = __builtin_amdgcn_mfma_f32_16x16x32_f16(qf[0][ks], bf, s[0][nb], 0, 0, 0);
                s[1][nb] = __builtin_amdgcn_mfma_f32_16x16x32_f16(qf[1][ks], bf, s[1][nb], 0, 0, 0);
            }
        }
        #pragma unroll
        for (int g = 0; g < 2; ++g)
            #pragma unroll
            for (int nb = 0; nb < 2; ++nb)
                #pragma unroll
                for (int r = 0; r < 4; ++r) {
                    float t = fminf(fmaf(s[g][nb][r], LOG2E, NSHIFT), 125.0f);
                    union { float f; uint32_t u; } pv; pv.f = exp2f(t);
                    unsigned short pt = (unsigned short)(pv.u >> 16);
                    lsum[g][r] += bf2f(pt);
                    Ps[wave][g * 16 + quad * 4 + r][nb * 16 + lo] = pt;
                }
        bf16x8 pf0 = *(const bf16x8*)(&Ps[wave][lo][quad * 8]);
        bf16x8 pf1 = *(const bf16x8*)(&Ps[wave][16 + lo][quad * 8]);
        #pragma unroll
        for (int nb = 0; nb < 8; ++nb) {
            bf16x8 vf = *(const bf16x8*)(&Vt[nb * 16 + lo][quad * 8]);
            oacc[0][nb] = __builtin_amdgcn_mfma_f32_16x16x32_bf16(pf0, vf, oacc[0][nb], 0, 0, 0);
            oacc[1][nb] = __builtin_amdgcn_mfma_f32_16x16x32_bf16(pf1, vf, oacc[1][nb], 0, 0, 0);
        }
    }
    #pragma unroll
    for (int g = 0; g < 2; ++g) {
        #pragma unroll
        for (int r = 0; r < 4; ++r) {
            float xr = lsum[g][r];
            #pragma unroll
            for (int m = 1; m < 16; m <<= 1) xr += __shfl_xor(xr, m, 64);
            lsum[g][r] = xr;
        }
        #pragma unroll
        for (int nb = 0; nb < 8; ++nb)
            #pragma unroll
            for (int r = 0; r < 4; ++r) {
                int m = b * 4096 + qbase + g * 16 + quad * 4 + r;
                part[((size_t)z * 16384 + m) * 128 + nb * 16 + lo] = f2bf(oacc[g][nb][r]);
            }
        if (lo == 0)
            #pragma unroll
            for (int r = 0; r < 4; ++r) {
                int m = b * 4096 + qbase + g * 16 + quad * 4 + r;
                lpart[(size_t)z * 16384 + m] = lsum[g][r];
            }
    }
}
#endif

// ---------------------------------------------------------------------------
// Kernel 3: combine partials; y = (o @ Wo) * gamma (unchanged from round 7).
// ---------------------------------------------------------------------------
__global__ __launch_bounds__(256) void outproj_kernel(
    const unsigned short* __restrict__ part,
    const float* __restrict__ lpart,
    const unsigned short* __restrict__ wot,
    const float* __restrict__ gamma,
    float* __restrict__ out,
    int nsplit)
{
    const int rowtile = blockIdx.x;
    const int tid  = threadIdx.x;
    const int lane = tid & 63, wave = tid >> 6;
    const int lo   = lane & 15, quad = lane >> 4;

    __shared__ __align__(16) unsigned short Os[64][136];
    __shared__ __align__(16) unsigned short WoT[128][136];

    #pragma unroll
    for (int i = 0; i < 4; ++i) {
        int flat = (i * 256 + tid) * 8;
        int row = flat >> 7, col = flat & 127;
        int m = rowtile * 64 + row;
        float acc8[8] = {0.f,0.f,0.f,0.f,0.f,0.f,0.f,0.f};
        float l = 0.f;
        for (int zz = 0; zz < nsplit; ++zz) {
            short8 t = *(const short8*)(part + ((size_t)zz * 16384 + m) * 128 + col);
            #pragma unroll
            for (int j = 0; j < 8; ++j) acc8[j] += bf2f((unsigned short)t[j]);
            l += lpart[(size_t)zz * 16384 + m];
        }
        float inv = 1.0f / l;
        short8 o8;
        #pragma unroll
        for (int j = 0; j < 8; ++j) o8[j] = (short)f2bf(acc8[j] * inv);
        *(short8*)(&Os[row][col]) = o8;
    }

    const int wc = tid >> 1, wa0 = (tid & 1) * 64;
    for (int ch = 0; ch < 2; ++ch) {
        if (ch) __syncthreads();
        #pragma unroll
        for (int j = 0; j < 8; ++j)
            *(short8*)(&WoT[wc][wa0 + j * 8]) =
                *(const short8*)(wot + (size_t)(ch * 128 + wc) * 128 + wa0 + j * 8);
        __syncthreads();

        f32x4 acc[8];
        #pragma unroll
        for (int i = 0; i < 8; ++i) acc[i] = (f32x4){0.f, 0.f, 0.f, 0.f};
        #pragma unroll
        for (int ks = 0; ks < 4; ++ks) {
            bf16x8 a = *(const bf16x8*)(&Os[wave * 16 + lo][ks * 32 + quad * 8]);
            #pragma unroll
            for (int nb = 0; nb < 8; ++nb) {
                bf16x8 bf = *(const bf16x8*)(&WoT[nb * 16 + lo][ks * 32 + quad * 8]);
                acc[nb] = __builtin_amdgcn_mfma_f32_16x16x32_bf16(a, bf, acc[nb], 0, 0, 0);
            }
        }
        #pragma unroll
        for (int nb = 0; nb < 8; ++nb) {
            int c = ch * 128 + nb * 16 + lo;
            float g = gamma[c];
            #pragma unroll
            for (int r = 0; r < 4; ++r) {
                int m = rowtile * 64 + wave * 16 + quad * 4 + r;
                out[(size_t)m * 256 + c] = acc[nb][r] * g;
            }
        }
    }
}

// ---------------------------------------------------------------------------
extern "C" void kernel_launch(void* const* d_in, const int* in_sizes, int n_in,
                              void* d_out, int out_size, void* d_ws, size_t ws_size,
                              hipStream_t stream) {
    const float* x  = (const float*)d_in[0];
    const float* Wq = (const float*)d_in[1];
    const float* Wk = (const float*)d_in[2];
    const float* Wv = (const float*)d_in[3];
    const float* Wo = (const float*)d_in[4];
    const float* wg = (const float*)d_in[5];
    float* out = (float*)d_out;

    unsigned short* ws = (unsigned short*)d_ws;
    const int nsplit = (ws_size >= (size_t)47000000) ? 8 : 4;
    const int chunk  = 4096 / nsplit;

    unsigned short* qkv_ws = ws;
    unsigned short* part   = ws + (size_t)3 * 2097152u;
    unsigned short* wt_hi  = part;
    unsigned short* wt_lo  = part + 98304u;
    float* lpart = (float*)(part + (size_t)nsplit * 2097152u);
    unsigned short* wot = (unsigned short*)(lpart + (size_t)nsplit * 16384u);
    float* gamma = (float*)(wot + 32768u);

    prep_kernel<<<dim3(17), 256, 0, stream>>>(Wq, Wk, Wv, Wo, wg, wt_hi, wt_lo, wot, gamma);
    qkv_kernel<<<dim3(256, 3), 256, 0, stream>>>(x, wt_hi, wt_lo, qkv_ws);
    attn_kernel<<<dim3(4, 32, nsplit), 256, 0, stream>>>(qkv_ws, part, lpart, chunk);
    outproj_kernel<<<dim3(256), 256, 0, stream>>>(part, lpart, wot, gamma, out, nsplit);
}

// Round 9
// 170.703 us; speedup vs baseline: 1.0618x; 1.0431x over previous
//
#include <hip/hip_runtime.h>
#include <hip/hip_bf16.h>
#include <cstdint>
#include <cstddef>

typedef __bf16 bf16x8 __attribute__((ext_vector_type(8)));
typedef _Float16 f16x8 __attribute__((ext_vector_type(8)));
typedef short short8 __attribute__((ext_vector_type(8)));
typedef short short4v __attribute__((ext_vector_type(4)));
typedef float f32x4 __attribute__((ext_vector_type(4)));

#if __has_builtin(__builtin_amdgcn_mfma_f32_16x16x16bf16_1k)
  #define HAVE_K16 1
  #define MFMA16BF(a,b,c) __builtin_amdgcn_mfma_f32_16x16x16bf16_1k((a),(b),(c),0,0,0)
#elif __has_builtin(__builtin_amdgcn_mfma_f32_16x16x16_bf16)
  #define HAVE_K16 1
  #define MFMA16BF(a,b,c) __builtin_amdgcn_mfma_f32_16x16x16_bf16((a),(b),(c),0,0,0)
#else
  #define HAVE_K16 0
#endif

#if __has_builtin(__builtin_amdgcn_exp2f)
  #define EXP2F(x) __builtin_amdgcn_exp2f(x)
#else
  #define EXP2F(x) exp2f(x)
#endif

__device__ __forceinline__ unsigned short f2bf(float f) {
    union { float f; uint32_t u; } v; v.f = f;
    uint32_t u = v.u;
    return (unsigned short)((u + 0x7FFFu + ((u >> 16) & 1u)) >> 16);
}
__device__ __forceinline__ float bf2f(unsigned short h) {
    union { uint32_t u; float f; } v; v.u = ((uint32_t)h) << 16;
    return v.f;
}
__device__ __forceinline__ unsigned short f2h(float f) {
    union { _Float16 h; unsigned short u; } v; v.h = (_Float16)f;
    return v.u;
}

// ---------------------------------------------------------------------------
// Kernel 0: preconvert weights (unchanged).
// ---------------------------------------------------------------------------
__global__ __launch_bounds__(256) void prep_kernel(
    const float* __restrict__ Wq, const float* __restrict__ Wk,
    const float* __restrict__ Wv, const float* __restrict__ Wo,
    const float* __restrict__ wg,
    unsigned short* __restrict__ wt_hi,
    unsigned short* __restrict__ wt_lo,
    unsigned short* __restrict__ wot,
    float* __restrict__ gamma)
{
    const int bid = blockIdx.x, t = threadIdx.x;
    __shared__ __align__(16) unsigned short Th[128][72], Tl[128][72];
    if (bid < 12) {
        const int proj = bid >> 2, kc = bid & 3;
        const float* W = (proj == 0) ? Wq : ((proj == 1) ? Wk : Wv);
        for (int r = 0; r < 32; ++r) {
            int idx = r * 256 + t;
            int kk = idx >> 7, n = idx & 127;
            float w = W[(size_t)(kc * 64 + kk) * 128 + n];
            unsigned short h = f2bf(w);
            Th[n][kk] = h;
            Tl[n][kk] = f2bf(w - bf2f(h));
        }
        __syncthreads();
        int n = t >> 1, k0 = (t & 1) * 32;
        size_t off = (size_t)proj * 32768 + (size_t)kc * 8192 + (size_t)n * 64 + k0;
        #pragma unroll
        for (int j = 0; j < 4; ++j) {
            *(short8*)(wt_hi + off + j * 8) = *(const short8*)(&Th[n][k0 + j * 8]);
            *(short8*)(wt_lo + off + j * 8) = *(const short8*)(&Tl[n][k0 + j * 8]);
        }
    } else if (bid < 16) {
        const int c0 = (bid - 12) * 64;
        unsigned short* T = &Th[0][0];
        for (int r = 0; r < 32; ++r) {
            int idx = r * 256 + t;
            int a = idx >> 6, cc = idx & 63;
            T[cc * 136 + a] = f2bf(Wo[(size_t)a * 256 + c0 + cc]);
        }
        __syncthreads();
        int cc = t >> 2, a0 = (t & 3) * 32;
        #pragma unroll
        for (int j = 0; j < 4; ++j)
            *(short8*)(wot + (size_t)(c0 + cc) * 128 + a0 + j * 8) =
                *(const short8*)(&T[cc * 136 + a0 + j * 8]);
    } else {
        float g = 1.0f + wg[t];
        if (g < 0.f) g = 0.f;
        gamma[t] = tanhf(g);
    }
}

// ---------------------------------------------------------------------------
// Kernel 1: q/k/v projections (unchanged).
// ---------------------------------------------------------------------------
__global__ __launch_bounds__(256) void qkv_kernel(
    const float* __restrict__ x,
    const unsigned short* __restrict__ wt_hi,
    const unsigned short* __restrict__ wt_lo,
    unsigned short* __restrict__ qkv_ws)
{
    const int rowtile = blockIdx.x;
    const int proj    = blockIdx.y;
    unsigned short* outqk = qkv_ws + (size_t)proj * 2097152u;
    unsigned short* vt    = qkv_ws + (size_t)2 * 2097152u;
    const bool need_lo = (proj < 2);

    const int tid  = threadIdx.x;
    const int lane = tid & 63, wave = tid >> 6;
    const int lo   = lane & 15, quad = lane >> 4;

    __shared__ __align__(16) unsigned short Xh[64][72], Xl[64][72];
    __shared__ __align__(16) unsigned short Wh[128][72], Wl[128][72];

    f32x4 acc[8];
    #pragma unroll
    for (int i = 0; i < 8; ++i) acc[i] = (f32x4){0.f, 0.f, 0.f, 0.f};

    const int wn = tid >> 1, wk0 = (tid & 1) * 32;

    for (int kc = 0; kc < 4; ++kc) {
        __syncthreads();
        #pragma unroll
        for (int i = 0; i < 4; ++i) {
            int flat4 = (i * 256 + tid) * 4;
            int row = flat4 >> 6, col = flat4 & 63;
            float4 tv4 = *(const float4*)(x + (size_t)(rowtile * 64 + row) * 256 + kc * 64 + col);
            float tv[4] = {tv4.x, tv4.y, tv4.z, tv4.w};
            short4v h, l;
            #pragma unroll
            for (int j = 0; j < 4; ++j) {
                unsigned short hj = f2bf(tv[j]);
                h[j] = (short)hj;
                l[j] = (short)f2bf(tv[j] - bf2f(hj));
            }
            *(short4v*)(&Xh[row][col]) = h;
            if (need_lo) *(short4v*)(&Xl[row][col]) = l;
        }
        {
            const size_t off = (size_t)proj * 32768 + (size_t)kc * 8192 + (size_t)wn * 64 + wk0;
            #pragma unroll
            for (int j = 0; j < 4; ++j)
                *(short8*)(&Wh[wn][wk0 + j * 8]) = *(const short8*)(wt_hi + off + j * 8);
            if (need_lo) {
                #pragma unroll
                for (int j = 0; j < 4; ++j)
                    *(short8*)(&Wl[wn][wk0 + j * 8]) = *(const short8*)(wt_lo + off + j * 8);
            }
        }
        __syncthreads();
        #pragma unroll
        for (int ks = 0; ks < 2; ++ks) {
            bf16x8 ah = *(const bf16x8*)(&Xh[wave * 16 + lo][ks * 32 + quad * 8]);
            #pragma unroll
            for (int nb = 0; nb < 8; ++nb) {
                bf16x8 bh = *(const bf16x8*)(&Wh[nb * 16 + lo][ks * 32 + quad * 8]);
                acc[nb] = __builtin_amdgcn_mfma_f32_16x16x32_bf16(ah, bh, acc[nb], 0, 0, 0);
                if (need_lo) {
                    bf16x8 al = *(const bf16x8*)(&Xl[wave * 16 + lo][ks * 32 + quad * 8]);
                    bf16x8 bl = *(const bf16x8*)(&Wl[nb * 16 + lo][ks * 32 + quad * 8]);
                    acc[nb] = __builtin_amdgcn_mfma_f32_16x16x32_bf16(al, bh, acc[nb], 0, 0, 0);
                    acc[nb] = __builtin_amdgcn_mfma_f32_16x16x32_bf16(ah, bl, acc[nb], 0, 0, 0);
                }
            }
        }
    }
    if (proj < 2) {
        #pragma unroll
        for (int nb = 0; nb < 8; ++nb) {
            #pragma unroll
            for (int r = 0; r < 4; ++r) {
                float v = acc[nb][r];
                v = (v >= 0.f) ? v : 0.2f * v;
                int m = rowtile * 64 + wave * 16 + quad * 4 + r;
                outqk[(size_t)m * 128 + nb * 16 + lo] = f2h(v);
            }
        }
    } else {
        const int b  = rowtile >> 6;
        const int sb = (rowtile & 63) * 64;
        #pragma unroll
        for (int nb = 0; nb < 8; ++nb) {
            #pragma unroll
            for (int r = 0; r < 4; ++r) {
                float v = acc[nb][r];
                v = (v >= 0.f) ? v : 0.2f * v;
                int seq = sb + wave * 16 + quad * 4 + r;
                int d   = nb * 16 + lo;
                vt[(size_t)b * 524288 + (size_t)d * 4096 + seq] = f2bf(v);
            }
        }
    }
}

#if HAVE_K16
// ---------------------------------------------------------------------------
// Kernel 2: flash attention, software-pipelined one-deep:
//   iter t: QK(t) MFMAs, then PV(t-1) MFMAs (contiguous on MFMA pipe, fills
//   QK(t) latency), barrier, stage tile t+1 into the vacated LDS buffer,
//   prefetch tile t+2 to regs, exp(t) on VALU (overlaps MFMA drain), barrier.
// P in registers (S^T C-layout == 16x16x16 A-layout). Double-buffered K/V LDS.
// grid (4, 32, nsplit), block 256.
// ---------------------------------------------------------------------------
__global__ __launch_bounds__(256) void attn_kernel(
    const unsigned short* __restrict__ qkv_ws,
    unsigned short* __restrict__ part,   // [nsplit][16384][128] bf16
    float* __restrict__ lpart,           // [nsplit][16384] fp32
    int chunk)
{
    const int b  = blockIdx.x;
    const int qt = blockIdx.y;
    const int z  = blockIdx.z;
    const int tid  = threadIdx.x;
    const int lane = tid & 63, wave = tid >> 6;
    const int lo   = lane & 15, quad = lane >> 4;

    const unsigned short* q  = qkv_ws;
    const unsigned short* k  = qkv_ws + 2097152u;
    const unsigned short* vt = qkv_ws + (size_t)2 * 2097152u + (size_t)b * 524288u;

    __shared__ __align__(16) unsigned short Ks[2][32][136];  // K fp16 [s][d]
    __shared__ __align__(16) unsigned short Vt[2][128][40];  // V^T bf16 quad-interleaved

    const int qbase = qt * 128 + wave * 32;
    f16x8 qf[2][4];
    #pragma unroll
    for (int g = 0; g < 2; ++g)
        #pragma unroll
        for (int ks = 0; ks < 4; ++ks)
            qf[g][ks] = *(const f16x8*)(q + ((size_t)(b * 4096 + qbase + g * 16 + lo)) * 128
                                          + ks * 32 + quad * 8);

    f32x4 oacc[2][8];
    #pragma unroll
    for (int g = 0; g < 2; ++g)
        #pragma unroll
        for (int i = 0; i < 8; ++i) oacc[g][i] = (f32x4){0.f, 0.f, 0.f, 0.f};
    float Lsum[2] = {1e-30f, 1e-30f};

    const float LOG2E  = 1.44269504088896f;
    const float NSHIFT = -40.0f * 1.44269504088896f;

    // staging maps
    const int krow0 = tid >> 4, kcol0 = (tid & 15) * 8;
    const int krow1 = 16 + (tid >> 4);
    const int vd = tid >> 2, vc = tid & 3;
    const int vst  = vc >> 1;
    const int colA = ((2 * vc) & 3) * 8 + vst * 4;
    const int colB = ((2 * vc + 1) & 3) * 8 + vst * 4;

    const int niter = chunk >> 5;
    const int sbase = z * chunk;

    short8 ka, kb, va, vb;
    // stage tile 0 into buf 0
    ka = *(const short8*)(k + ((size_t)(b * 4096 + sbase + krow0)) * 128 + kcol0);
    kb = *(const short8*)(k + ((size_t)(b * 4096 + sbase + krow1)) * 128 + kcol0);
    va = *(const short8*)(vt + (size_t)vd * 4096 + sbase + vc * 8);
    vb = *(const short8*)(vt + (size_t)(vd + 64) * 4096 + sbase + vc * 8);
    *(short8*)(&Ks[0][krow0][kcol0]) = ka;
    *(short8*)(&Ks[0][krow1][kcol0]) = kb;
    {
        short4v a0 = {va[0], va[1], va[2], va[3]}, a1 = {va[4], va[5], va[6], va[7]};
        short4v b0 = {vb[0], vb[1], vb[2], vb[3]}, b1 = {vb[4], vb[5], vb[6], vb[7]};
        *(short4v*)(&Vt[0][vd][colA])      = a0;
        *(short4v*)(&Vt[0][vd][colB])      = a1;
        *(short4v*)(&Vt[0][vd + 64][colA]) = b0;
        *(short4v*)(&Vt[0][vd + 64][colB]) = b1;
    }
    // prefetch tile 1 into regs
    if (1 < niter) {
        const int s1 = sbase + 32;
        ka = *(const short8*)(k + ((size_t)(b * 4096 + s1 + krow0)) * 128 + kcol0);
        kb = *(const short8*)(k + ((size_t)(b * 4096 + s1 + krow1)) * 128 + kcol0);
        va = *(const short8*)(vt + (size_t)vd * 4096 + s1 + vc * 8);
        vb = *(const short8*)(vt + (size_t)(vd + 64) * 4096 + s1 + vc * 8);
    }
    __syncthreads();

    short4v Pp[2][2];   // P(t-1), A-frag layout (k = quad*4 + j)

    for (int kt = 0; kt < niter; ++kt) {
        const int cur = kt & 1, oth = cur ^ 1;

        // 1. QK(t): S^T = K·Q^T, A = K-frag (LDS), B = Q-frag (regs). 16 MFMAs K=32.
        f32x4 sT[2][2];
        sT[0][0] = (f32x4){0.f,0.f,0.f,0.f}; sT[0][1] = (f32x4){0.f,0.f,0.f,0.f};
        sT[1][0] = (f32x4){0.f,0.f,0.f,0.f}; sT[1][1] = (f32x4){0.f,0.f,0.f,0.f};
        #pragma unroll
        for (int ks = 0; ks < 4; ++ks) {
            #pragma unroll
            for (int st = 0; st < 2; ++st) {
                f16x8 kf = *(const f16x8*)(&Ks[cur][st * 16 + lo][ks * 32 + quad * 8]);
                sT[0][st] = __builtin_amdgcn_mfma_f32_16x16x32_f16(kf, qf[0][ks], sT[0][st], 0, 0, 0);
                sT[1][st] = __builtin_amdgcn_mfma_f32_16x16x32_f16(kf, qf[1][ks], sT[1][st], 0, 0, 0);
            }
        }
        // 2. PV(t-1): fills the MFMA pipe while QK(t) drains. Reads Vt[oth].
        if (kt > 0) {
            #pragma unroll
            for (int nb = 0; nb < 8; ++nb) {
                short8 vv = *(const short8*)(&Vt[oth][nb * 16 + lo][quad * 8]);
                short4v v0 = {vv[0], vv[1], vv[2], vv[3]};
                short4v v1 = {vv[4], vv[5], vv[6], vv[7]};
                #pragma unroll
                for (int g = 0; g < 2; ++g) {
                    oacc[g][nb] = MFMA16BF(Pp[g][0], v0, oacc[g][nb]);
                    oacc[g][nb] = MFMA16BF(Pp[g][1], v1, oacc[g][nb]);
                }
            }
        }
        // 3. all waves done reading buf[oth]
        __syncthreads();
        // 4. stage tile t+1 into buf[oth]
        if (kt + 1 < niter) {
            *(short8*)(&Ks[oth][krow0][kcol0]) = ka;
            *(short8*)(&Ks[oth][krow1][kcol0]) = kb;
            short4v a0 = {va[0], va[1], va[2], va[3]}, a1 = {va[4], va[5], va[6], va[7]};
            short4v b0 = {vb[0], vb[1], vb[2], vb[3]}, b1 = {vb[4], vb[5], vb[6], vb[7]};
            *(short4v*)(&Vt[oth][vd][colA])      = a0;
            *(short4v*)(&Vt[oth][vd][colB])      = a1;
            *(short4v*)(&Vt[oth][vd + 64][colA]) = b0;
            *(short4v*)(&Vt[oth][vd + 64][colB]) = b1;
        }
        // 5. prefetch tile t+2 into regs
        if (kt + 2 < niter) {
            const int s2 = sbase + (kt + 2) * 32;
            ka = *(const short8*)(k + ((size_t)(b * 4096 + s2 + krow0)) * 128 + kcol0);
            kb = *(const short8*)(k + ((size_t)(b * 4096 + s2 + krow1)) * 128 + kcol0);
            va = *(const short8*)(vt + (size_t)vd * 4096 + s2 + vc * 8);
            vb = *(const short8*)(vt + (size_t)(vd + 64) * 4096 + s2 + vc * 8);
        }
        // 6. exp(t) on VALU — overlaps the PV/QK MFMA drain
        #pragma unroll
        for (int g = 0; g < 2; ++g) {
            #pragma unroll
            for (int st = 0; st < 2; ++st) {
                #pragma unroll
                for (int r = 0; r < 4; ++r) {
                    float t = fminf(fmaf(sT[g][st][r], LOG2E, NSHIFT), 125.0f);
                    union { float f; uint32_t u; } pv; pv.f = EXP2F(t);
                    unsigned short pt = (unsigned short)(pv.u >> 16);
                    Lsum[g] += bf2f(pt);
                    Pp[g][st][r] = (short)pt;
                }
            }
        }
        // 7. make stage-writes visible before next iter's QK reads
        __syncthreads();
    }
    // final PV(niter-1): Vt[(niter-1)&1] is untouched (no stage in last iter)
    {
        const int last = (niter - 1) & 1;
        #pragma unroll
        for (int nb = 0; nb < 8; ++nb) {
            short8 vv = *(const short8*)(&Vt[last][nb * 16 + lo][quad * 8]);
            short4v v0 = {vv[0], vv[1], vv[2], vv[3]};
            short4v v1 = {vv[4], vv[5], vv[6], vv[7]};
            #pragma unroll
            for (int g = 0; g < 2; ++g) {
                oacc[g][nb] = MFMA16BF(Pp[g][0], v0, oacc[g][nb]);
                oacc[g][nb] = MFMA16BF(Pp[g][1], v1, oacc[g][nb]);
            }
        }
    }

    // Lsum: lane holds partial for m = lo; reduce over the 4 quad replicas.
    #pragma unroll
    for (int g = 0; g < 2; ++g) {
        float xr = Lsum[g];
        xr += __shfl_xor(xr, 16, 64);
        xr += __shfl_xor(xr, 32, 64);
        Lsum[g] = xr;
    }
    #pragma unroll
    for (int g = 0; g < 2; ++g) {
        #pragma unroll
        for (int nb = 0; nb < 8; ++nb) {
            #pragma unroll
            for (int r = 0; r < 4; ++r) {
                int m = b * 4096 + qbase + g * 16 + quad * 4 + r;
                part[((size_t)z * 16384 + m) * 128 + nb * 16 + lo] = f2bf(oacc[g][nb][r]);
            }
        }
        if (lane < 16) {
            int m = b * 4096 + qbase + g * 16 + lane;
            lpart[(size_t)z * 16384 + m] = Lsum[g];
        }
    }
}
#else
// ---------------------------------------------------------------------------
// Fallback (no K=16 bf16 MFMA builtin): round-7 attn kernel, verbatim.
// ---------------------------------------------------------------------------
__global__ __launch_bounds__(256) void attn_kernel(
    const unsigned short* __restrict__ qkv_ws,
    unsigned short* __restrict__ part,
    float* __restrict__ lpart,
    int chunk)
{
    const int b  = blockIdx.x;
    const int qt = blockIdx.y;
    const int z  = blockIdx.z;
    const int tid  = threadIdx.x;
    const int lane = tid & 63, wave = tid >> 6;
    const int lo   = lane & 15, quad = lane >> 4;

    const unsigned short* q  = qkv_ws;
    const unsigned short* k  = qkv_ws + 2097152u;
    const unsigned short* vt = qkv_ws + (size_t)2 * 2097152u + (size_t)b * 524288u;

    __shared__ __align__(16) unsigned short Ks[32][136];
    __shared__ __align__(16) unsigned short Vt[128][40];
    __shared__ __align__(16) unsigned short Ps[4][32][40];

    const int qbase = qt * 128 + wave * 32;
    f16x8 qf[2][4];
    #pragma unroll
    for (int g = 0; g < 2; ++g)
        #pragma unroll
        for (int ks = 0; ks < 4; ++ks)
            qf[g][ks] = *(const f16x8*)(q + ((size_t)(b * 4096 + qbase + g * 16 + lo)) * 128
                                          + ks * 32 + quad * 8);
    f32x4 oacc[2][8];
    #pragma unroll
    for (int g = 0; g < 2; ++g)
        #pragma unroll
        for (int i = 0; i < 8; ++i) oacc[g][i] = (f32x4){0.f, 0.f, 0.f, 0.f};
    float lsum[2][4];
    #pragma unroll
    for (int g = 0; g < 2; ++g)
        #pragma unroll
        for (int r = 0; r < 4; ++r) lsum[g][r] = 1e-30f;

    const float LOG2E  = 1.44269504088896f;
    const float NSHIFT = -40.0f * 1.44269504088896f;

    const int krow0 = tid >> 4, kcol0 = (tid & 15) * 8;
    const int krow1 = 16 + (tid >> 4);
    const int vd0 = tid >> 2, vs0 = (tid & 3) * 8;

    const int niter = chunk >> 5;
    const int sbase = z * chunk;

    short8 ka, kb, va, vb;
    ka = *(const short8*)(k + ((size_t)(b * 4096 + sbase + krow0)) * 128 + kcol0);
    kb = *(const short8*)(k + ((size_t)(b * 4096 + sbase + krow1)) * 128 + kcol0);
    va = *(const short8*)(vt + (size_t)vd0 * 4096 + sbase + vs0);
    vb = *(const short8*)(vt + (size_t)(vd0 + 64) * 4096 + sbase + vs0);

    for (int kt = 0; kt < niter; ++kt) {
        __syncthreads();
        *(short8*)(&Ks[krow0][kcol0]) = ka;
        *(short8*)(&Ks[krow1][kcol0]) = kb;
        *(short8*)(&Vt[vd0][vs0]) = va;
        *(short8*)(&Vt[vd0 + 64][vs0]) = vb;
        __syncthreads();
        if (kt + 1 < niter) {
            const int s1 = sbase + (kt + 1) * 32;
            ka = *(const short8*)(k + ((size_t)(b * 4096 + s1 + krow0)) * 128 + kcol0);
            kb = *(const short8*)(k + ((size_t)(b * 4096 + s1 + krow1)) * 128 + kcol0);
            va = *(const short8*)(vt + (size_t)vd0 * 4096 + s1 + vs0);
            vb = *(const short8*)(vt + (size_t)(vd0 + 64) * 4096 + s1 + vs0);
        }
        f32x4 s[2][2];
        s[0][0] = (f32x4){0.f,0.f,0.f,0.f}; s[0][1] = (f32x4){0.f,0.f,0.f,0.f};
        s[1][0] = (f32x4){0.f,0.f,0.f,0.f}; s[1][1] = (f32x4){0.f,0.f,0.f,0.f};
        #pragma unroll
        for (int ks = 0; ks < 4; ++ks) {
            #pragma unroll
            for (int nb = 0; nb < 2; ++nb) {
                f16x8 bf = *(const f16x8*)(&Ks[nb * 16 + lo][ks * 32 + quad * 8]);
                s[0][nb] = __builtin_amdgcn_mfma_f32_16x16x32_f16(qf[0][ks], bf, s[0][nb], 0, 0, 0);
                s[1][nb] = __builtin_amdgcn_mfma_f32_16x16x32_f16(qf[1][ks], bf, s[1][nb], 0, 0, 0);
            }
        }
        #pragma unroll
        for (int g = 0; g < 2; ++g)
            #pragma unroll
            for (int nb = 0; nb < 2; ++nb)
                #pragma unroll
                for (int r = 0; r < 4; ++r) {
                    float t = fminf(fmaf(s[g][nb][r], LOG2E, NSHIFT), 125.0f);
                    union { float f; uint32_t u; } pv; pv.f = EXP2F(t);
                    unsigned short pt = (unsigned short)(pv.u >> 16);
                    lsum[g][r] += bf2f(pt);
                    Ps[wave][g * 16 + quad * 4 + r][nb * 16 + lo] = pt;
                }
        bf16x8 pf0 = *(const bf16x8*)(&Ps[wave][lo][quad * 8]);
        bf16x8 pf1 = *(const bf16x8*)(&Ps[wave][16 + lo][quad * 8]);
        #pragma unroll
        for (int nb = 0; nb < 8; ++nb) {
            bf16x8 vf = *(const bf16x8*)(&Vt[nb * 16 + lo][quad * 8]);
            oacc[0][nb] = __builtin_amdgcn_mfma_f32_16x16x32_bf16(pf0, vf, oacc[0][nb], 0, 0, 0);
            oacc[1][nb] = __builtin_amdgcn_mfma_f32_16x16x32_bf16(pf1, vf, oacc[1][nb], 0, 0, 0);
        }
    }
    #pragma unroll
    for (int g = 0; g < 2; ++g) {
        #pragma unroll
        for (int r = 0; r < 4; ++r) {
            float xr = lsum[g][r];
            #pragma unroll
            for (int m = 1; m < 16; m <<= 1) xr += __shfl_xor(xr, m, 64);
            lsum[g][r] = xr;
        }
        #pragma unroll
        for (int nb = 0; nb < 8; ++nb)
            #pragma unroll
            for (int r = 0; r < 4; ++r) {
                int m = b * 4096 + qbase + g * 16 + quad * 4 + r;
                part[((size_t)z * 16384 + m) * 128 + nb * 16 + lo] = f2bf(oacc[g][nb][r]);
            }
        if (lo == 0)
            #pragma unroll
            for (int r = 0; r < 4; ++r) {
                int m = b * 4096 + qbase + g * 16 + quad * 4 + r;
                lpart[(size_t)z * 16384 + m] = lsum[g][r];
            }
    }
}
#endif

// ---------------------------------------------------------------------------
// Kernel 3: combine partials; y = (o @ Wo) * gamma (unchanged).
// ---------------------------------------------------------------------------
__global__ __launch_bounds__(256) void outproj_kernel(
    const unsigned short* __restrict__ part,
    const float* __restrict__ lpart,
    const unsigned short* __restrict__ wot,
    const float* __restrict__ gamma,
    float* __restrict__ out,
    int nsplit)
{
    const int rowtile = blockIdx.x;
    const int tid  = threadIdx.x;
    const int lane = tid & 63, wave = tid >> 6;
    const int lo   = lane & 15, quad = lane >> 4;

    __shared__ __align__(16) unsigned short Os[64][136];
    __shared__ __align__(16) unsigned short WoT[128][136];

    #pragma unroll
    for (int i = 0; i < 4; ++i) {
        int flat = (i * 256 + tid) * 8;
        int row = flat >> 7, col = flat & 127;
        int m = rowtile * 64 + row;
        float acc8[8] = {0.f,0.f,0.f,0.f,0.f,0.f,0.f,0.f};
        float l = 0.f;
        for (int zz = 0; zz < nsplit; ++zz) {
            short8 t = *(const short8*)(part + ((size_t)zz * 16384 + m) * 128 + col);
            #pragma unroll
            for (int j = 0; j < 8; ++j) acc8[j] += bf2f((unsigned short)t[j]);
            l += lpart[(size_t)zz * 16384 + m];
        }
        float inv = 1.0f / l;
        short8 o8;
        #pragma unroll
        for (int j = 0; j < 8; ++j) o8[j] = (short)f2bf(acc8[j] * inv);
        *(short8*)(&Os[row][col]) = o8;
    }

    const int wc = tid >> 1, wa0 = (tid & 1) * 64;
    for (int ch = 0; ch < 2; ++ch) {
        if (ch) __syncthreads();
        #pragma unroll
        for (int j = 0; j < 8; ++j)
            *(short8*)(&WoT[wc][wa0 + j * 8]) =
                *(const short8*)(wot + (size_t)(ch * 128 + wc) * 128 + wa0 + j * 8);
        __syncthreads();

        f32x4 acc[8];
        #pragma unroll
        for (int i = 0; i < 8; ++i) acc[i] = (f32x4){0.f, 0.f, 0.f, 0.f};
        #pragma unroll
        for (int ks = 0; ks < 4; ++ks) {
            bf16x8 a = *(const bf16x8*)(&Os[wave * 16 + lo][ks * 32 + quad * 8]);
            #pragma unroll
            for (int nb = 0; nb < 8; ++nb) {
                bf16x8 bf = *(const bf16x8*)(&WoT[nb * 16 + lo][ks * 32 + quad * 8]);
                acc[nb] = __builtin_amdgcn_mfma_f32_16x16x32_bf16(a, bf, acc[nb], 0, 0, 0);
            }
        }
        #pragma unroll
        for (int nb = 0; nb < 8; ++nb) {
            int c = ch * 128 + nb * 16 + lo;
            float g = gamma[c];
            #pragma unroll
            for (int r = 0; r < 4; ++r) {
                int m = rowtile * 64 + wave * 16 + quad * 4 + r;
                out[(size_t)m * 256 + c] = acc[nb][r] * g;
            }
        }
    }
}

// ---------------------------------------------------------------------------
extern "C" void kernel_launch(void* const* d_in, const int* in_sizes, int n_in,
                              void* d_out, int out_size, void* d_ws, size_t ws_size,
                              hipStream_t stream) {
    const float* x  = (const float*)d_in[0];
    const float* Wq = (const float*)d_in[1];
    const float* Wk = (const float*)d_in[2];
    const float* Wv = (const float*)d_in[3];
    const float* Wo = (const float*)d_in[4];
    const float* wg = (const float*)d_in[5];
    float* out = (float*)d_out;

    unsigned short* ws = (unsigned short*)d_ws;
    const int nsplit = (ws_size >= (size_t)47000000) ? 8 : 4;
    const int chunk  = 4096 / nsplit;

    unsigned short* qkv_ws = ws;
    unsigned short* part   = ws + (size_t)3 * 2097152u;
    unsigned short* wt_hi  = part;
    unsigned short* wt_lo  = part + 98304u;
    float* lpart = (float*)(part + (size_t)nsplit * 2097152u);
    unsigned short* wot = (unsigned short*)(lpart + (size_t)nsplit * 16384u);
    float* gamma = (float*)(wot + 32768u);

    prep_kernel<<<dim3(17), 256, 0, stream>>>(Wq, Wk, Wv, Wo, wg, wt_hi, wt_lo, wot, gamma);
    qkv_kernel<<<dim3(256, 3), 256, 0, stream>>>(x, wt_hi, wt_lo, qkv_ws);
    attn_kernel<<<dim3(4, 32, nsplit), 256, 0, stream>>>(qkv_ws, part, lpart, chunk);
    outproj_kernel<<<dim3(256), 256, 0, stream>>>(part, lpart, wot, gamma, out, nsplit);
}